// Round 3
// baseline (2987.982 us; speedup 1.0000x reference)
//
#include <hip/hip_runtime.h>
#include <hip/hip_bf16.h>

#define BB 4096
#define TT 512
#define HH 256

typedef __bf16 bf16x8 __attribute__((ext_vector_type(8)));
typedef float f32x4 __attribute__((ext_vector_type(4)));

#define NREG 40   // fragments per wave in VGPRs (cc 0..4)
#define NLDS 16   // fragments per wave in LDS   (cc 5..6)
// cc 7 (8 frags/wave) streamed from L2 each step

// Reorder w_hh [1024][256] fp32 -> bf16 fragment-ordered buffer:
// frag (ctg,kt), lane l, elem e = w_hh[ctg*16 + (l&15)][kt*32 + 8*(l>>4) + e]
// stored at wB[((ctg*8+kt)*64 + l)*8 + e] so each frag load is one dwordx4/lane.
__global__ void prep_weights(const float* __restrict__ w_hh, __bf16* __restrict__ wB) {
    int idx = blockIdx.x * blockDim.x + threadIdx.x;
    if (idx >= 64 * 8 * 64) return;
    int l = idx & 63;
    int kt = (idx >> 6) & 7;
    int ctg = idx >> 9;
    int n = ctg * 16 + (l & 15);
    int k0 = kt * 32 + 8 * (l >> 4);
    const float* src = w_hh + n * HH + k0;
    __bf16* dst = wB + (size_t)idx * 8;
#pragma unroll
    for (int e = 0; e < 8; ++e) dst[e] = (__bf16)src[e];
}

__device__ __forceinline__ float sigmoid_f(float v) { return 1.f / (1.f + __expf(-v)); }
// NaN-safe tanh: 1 - 2/(exp(2v)+1) (handles exp overflow -> 1.0)
__device__ __forceinline__ float tanh_f(float v) { float e = __expf(2.f * v); return 1.f - 2.f / (e + 1.f); }

__global__ __launch_bounds__(512, 2) void lstm_fused(
    const float* __restrict__ x, const float* __restrict__ eps,
    const float* __restrict__ w_ih, const float* __restrict__ b_ih,
    const float* __restrict__ b_hh, const float* __restrict__ w_mean,
    const float* __restrict__ b_mean, const float* __restrict__ w_logvar,
    const float* __restrict__ b_logvar, const __bf16* __restrict__ wB,
    float* __restrict__ out)
{
    __shared__ __align__(16) __bf16 wlds[8][NLDS][512];   // 131072 B
    __shared__ __align__(16) __bf16 hbuf[2][16][264];     // 16896 B, ping-pong
    __shared__ __align__(16) __bf16 headw[8][512];        // 8192 B
    __shared__ float obuf[3][16][16];                     // 3072 B
    __shared__ float xb[2][16];                           // 128 B
    // total 159360 B <= 163840

    const int tid = threadIdx.x;
    const int w = tid >> 6;          // wave 0..7
    const int l = tid & 63;
    const int m0 = blockIdx.x * 16;  // batch base

    for (int i = tid; i < 2 * 16 * 264; i += 512) (&hbuf[0][0][0])[i] = (__bf16)0.f;

    // head column-tile: B-frag col 0 = w_mean, col 1 = w_logvar, cols 2-15 zero
    {
        int kt = tid >> 6, hl = tid & 63;
        int col = hl & 15;
        int k0 = kt * 32 + 8 * (hl >> 4);
        bf16x8 hw;
#pragma unroll
        for (int e = 0; e < 8; ++e) {
            float v = 0.f;
            if (col == 0) v = w_mean[k0 + e];
            else if (col == 1) v = w_logvar[k0 + e];
            hw[e] = (__bf16)v;
        }
        *(bf16x8*)&headw[kt][hl * 8] = hw;
    }

    // wave w owns ctg = w + 8p + 16g for cc = p*4+g (all 4 gates of its units)
    bf16x8 wreg[NREG];
#pragma unroll
    for (int cc = 0; cc < 7; ++cc) {
        const int ctg = w + 8 * (cc >> 2) + 16 * (cc & 3);
#pragma unroll
        for (int kt = 0; kt < 8; ++kt) {
            const int fi = cc * 8 + kt;
            bf16x8 v = *(const bf16x8*)(wB + ((size_t)(ctg * 8 + kt) * 64 + l) * 8);
            if (fi < NREG) wreg[fi] = v;
            else *(bf16x8*)&wlds[w][fi - NREG][l * 8] = v;
        }
    }

    // per-thread w_ih / fused bias in registers (each thread owns units
    // u_p = 128p + 16w + (l&15), all 4 gates)
    float wi[2][4], bi[2][4];
#pragma unroll
    for (int p = 0; p < 2; ++p) {
        const int u = 128 * p + 16 * w + (l & 15);
#pragma unroll
        for (int g = 0; g < 4; ++g) {
            wi[p][g] = w_ih[g * 256 + u];
            bi[p][g] = b_ih[g * 256 + u] + b_hh[g * 256 + u];
        }
    }

    if (tid < 16) xb[0][tid] = x[(size_t)(m0 + tid) * TT + 0];

    const float bm = b_mean[0], blv = b_logvar[0];
    const int arow = l & 15;
    const int ako = 8 * (l >> 4);
    const int r0 = (l >> 4) * 4;
    const int ctg7base = ((w + 56) * 8) * 64;  // streamed cc=7 tile

    float c[2][4];
#pragma unroll
    for (int p = 0; p < 2; ++p)
#pragma unroll
        for (int j = 0; j < 4; ++j) c[p][j] = 0.f;

    __syncthreads();

    for (int t = 0; t <= TT; ++t) {
        const int pb = t & 1;        // hbuf write buffer (h_t)
        const int rb = pb ^ 1;       // hbuf read buffer (h_{t-1})

        if (tid < 16 && t + 1 < TT)
            xb[(t + 1) & 1][tid] = x[(size_t)(m0 + tid) * TT + (t + 1)];

        // ---- GEMM over h_{t-1}: kt-outer, accs chained in registers ----
        f32x4 accs[8];
        f32x4 acch = {0.f, 0.f, 0.f, 0.f};
        const bool do_head = (w == 0) && (t >= 1);
        if (t < TT) {
#pragma unroll
            for (int cc = 0; cc < 8; ++cc) accs[cc] = (f32x4){0.f, 0.f, 0.f, 0.f};
#pragma unroll
            for (int kt = 0; kt < 8; ++kt) {
                bf16x8 sfr = *(const bf16x8*)(wB + (size_t)(ctg7base + kt * 64 + l) * 8);
                bf16x8 af = *(const bf16x8*)&hbuf[rb][arow][kt * 32 + ako];
#pragma unroll
                for (int cc = 0; cc < 7; ++cc) {
                    const int fi = cc * 8 + kt;
                    bf16x8 bfr;
                    if (fi < NREG) bfr = wreg[fi];
                    else bfr = *(const bf16x8*)&wlds[w][fi - NREG][l * 8];
                    accs[cc] = __builtin_amdgcn_mfma_f32_16x16x32_bf16(af, bfr, accs[cc], 0, 0, 0);
                }
                accs[7] = __builtin_amdgcn_mfma_f32_16x16x32_bf16(af, sfr, accs[7], 0, 0, 0);
                if (do_head)
                    acch = __builtin_amdgcn_mfma_f32_16x16x32_bf16(
                        af, *(const bf16x8*)&headw[kt][l * 8], acch, 0, 0, 0);
            }
        } else if (w == 0) {
#pragma unroll
            for (int kt = 0; kt < 8; ++kt) {
                bf16x8 af = *(const bf16x8*)&hbuf[rb][arow][kt * 32 + ako];
                acch = __builtin_amdgcn_mfma_f32_16x16x32_bf16(
                    af, *(const bf16x8*)&headw[kt][l * 8], acch, 0, 0, 0);
            }
        }

        // ---- heads epilogue for h_{t-1} (wave 0) ----
        if ((w == 0) && (t >= 1)) {
            const int slot = (t - 1) & 15;
#pragma unroll
            for (int j = 0; j < 4; ++j) {
                float lvn = __shfl(acch[j], (l & 48) | 1);  // col-1 lane = logvar
                if ((l & 15) == 0) {
                    const int r = r0 + j;
                    float mean = acch[j] + bm;
                    float lv = fminf(fmaxf(lvn + blv, -10.f), 2.f);
                    float ev = eps[(size_t)(m0 + r) * TT + (t - 1)];
                    obuf[0][r][slot] = mean + __expf(0.5f * lv) * ev;
                    obuf[1][r][slot] = mean;
                    obuf[2][r][slot] = lv;
                }
            }
        }

        // ---- elementwise LSTM cell, fully in registers ----
        if (t < TT) {
            float xv[4];
#pragma unroll
            for (int j = 0; j < 4; ++j) xv[j] = xb[t & 1][r0 + j];
#pragma unroll
            for (int p = 0; p < 2; ++p) {
                const int u = 128 * p + 16 * w + (l & 15);
#pragma unroll
                for (int j = 0; j < 4; ++j) {
                    float gi = accs[p * 4 + 0][j] + xv[j] * wi[p][0] + bi[p][0];
                    float gf = accs[p * 4 + 1][j] + xv[j] * wi[p][1] + bi[p][1];
                    float gg = accs[p * 4 + 2][j] + xv[j] * wi[p][2] + bi[p][2];
                    float go = accs[p * 4 + 3][j] + xv[j] * wi[p][3] + bi[p][3];
                    float ia = sigmoid_f(gi), fa = sigmoid_f(gf);
                    float ga = tanh_f(gg), oa = sigmoid_f(go);
                    float cn = fa * c[p][j] + ia * ga;
                    c[p][j] = cn;
                    hbuf[pb][r0 + j][u] = (__bf16)(oa * tanh_f(cn));
                }
            }
        }

        // ---- coalesced output flush every 16 steps ----
        if ((t & 15) == 0 && t > 0) {
            __syncthreads();  // wave0's obuf writes -> flushing waves
            if (tid < 192) {
                const int o = tid >> 6, rr = (tid >> 2) & 15, q = tid & 3;
                f32x4 v = *(const f32x4*)&obuf[o][rr][q * 4];
                float* dst = out + (size_t)o * BB * TT + (size_t)(m0 + rr) * TT + (t - 16) + q * 4;
                *(f32x4*)dst = v;
            }
        }
        __syncthreads();
    }
}

extern "C" void kernel_launch(void* const* d_in, const int* in_sizes, int n_in,
                              void* d_out, int out_size, void* d_ws, size_t ws_size,
                              hipStream_t stream) {
    const float* x = (const float*)d_in[0];
    const float* eps = (const float*)d_in[1];
    const float* w_ih = (const float*)d_in[2];
    const float* w_hh = (const float*)d_in[3];
    const float* b_ih = (const float*)d_in[4];
    const float* b_hh = (const float*)d_in[5];
    const float* w_mean = (const float*)d_in[6];
    const float* b_mean = (const float*)d_in[7];
    const float* w_logvar = (const float*)d_in[8];
    const float* b_logvar = (const float*)d_in[9];

    __bf16* wB = (__bf16*)d_ws;  // 512 KB fragment-ordered bf16 weights

    prep_weights<<<128, 256, 0, stream>>>(w_hh, wB);
    lstm_fused<<<256, 512, 0, stream>>>(x, eps, w_ih, b_ih, b_hh, w_mean, b_mean,
                                        w_logvar, b_logvar, wB, (float*)d_out);
}